// Round 4
// baseline (371.785 us; speedup 1.0000x reference)
//
#include <hip/hip_runtime.h>

// GraphSAGE 2-layer, N=100000, IN=HID=128, OUT=64, E=1.6M, fp32 in/out.
//   agg @ Wl == segsum((h@Wl)[src])/cnt  -> GEMM first, then gather-mean.
//   Intermediates (Y0, h, Y1) bf16; GEMMs bf16 MFMA 16x16x32, fp32 accum;
//   aggregation accumulates fp32.
// Round 4: 8-edges-per-thread MLP unroll in k_degree / k_fill (atomics and
// random reads issued back-to-back before any wait).

typedef short short8 __attribute__((ext_vector_type(8)));
typedef float f32x4 __attribute__((ext_vector_type(4)));

static __device__ __forceinline__ unsigned short f2bf(float f) {
    union { float f; unsigned u; } c; c.f = f;
    unsigned u = c.u + 0x7fffu + ((c.u >> 16) & 1u);   // RNE
    return (unsigned short)(u >> 16);
}
static __device__ __forceinline__ float bf2f(unsigned short b) {
    union { unsigned u; float f; } c; c.u = ((unsigned)b) << 16;
    return c.f;
}
static __device__ __forceinline__ float bf2f_s(short b) {
    return bf2f((unsigned short)b);
}

// ---------------- CSR build ----------------
// 8 edges/thread: issue 8 independent atomic-with-return before any wait.
__global__ __launch_bounds__(256) void k_degree(const int* __restrict__ dst,
                                                int* __restrict__ deg,
                                                int* __restrict__ rank, int E) {
    int base = (blockIdx.x * 256 + threadIdx.x) * 8;
    if (base + 8 <= E) {
        int4 d0 = *(const int4*)(dst + base);
        int4 d1 = *(const int4*)(dst + base + 4);
        int4 r0, r1;
        r0.x = atomicAdd(&deg[d0.x], 1);
        r0.y = atomicAdd(&deg[d0.y], 1);
        r0.z = atomicAdd(&deg[d0.z], 1);
        r0.w = atomicAdd(&deg[d0.w], 1);
        r1.x = atomicAdd(&deg[d1.x], 1);
        r1.y = atomicAdd(&deg[d1.y], 1);
        r1.z = atomicAdd(&deg[d1.z], 1);
        r1.w = atomicAdd(&deg[d1.w], 1);
        *(int4*)(rank + base) = r0;
        *(int4*)(rank + base + 4) = r1;
    } else {
        for (int e = base; e < E; ++e) rank[e] = atomicAdd(&deg[dst[e]], 1);
    }
}

__global__ __launch_bounds__(256) void k_scan1(const int* __restrict__ deg,
                                               int* __restrict__ rowptr,
                                               int* __restrict__ bsum, int N) {
    __shared__ int s[256];
    int t = threadIdx.x;
    int gid = blockIdx.x * 256 + t;
    int v = (gid < N) ? deg[gid] : 0;
    s[t] = v;
    __syncthreads();
    #pragma unroll
    for (int off = 1; off < 256; off <<= 1) {
        int x = (t >= off) ? s[t - off] : 0;
        __syncthreads();
        s[t] += x;
        __syncthreads();
    }
    if (gid < N) rowptr[gid] = s[t] - v;
    if (t == 255) bsum[blockIdx.x] = s[255];
}

__global__ __launch_bounds__(512) void k_scan2(int* __restrict__ bsum, int nb) {
    __shared__ int s[512];
    int t = threadIdx.x;
    int v = (t < nb) ? bsum[t] : 0;
    s[t] = v;
    __syncthreads();
    #pragma unroll
    for (int off = 1; off < 512; off <<= 1) {
        int x = (t >= off) ? s[t - off] : 0;
        __syncthreads();
        s[t] += x;
        __syncthreads();
    }
    if (t < nb) bsum[t] = s[t] - v;
}

__global__ __launch_bounds__(256) void k_scan3(int* __restrict__ rowptr,
                                               const int* __restrict__ bsum, int N) {
    int gid = blockIdx.x * 256 + threadIdx.x;
    if (gid < N) rowptr[gid] += bsum[blockIdx.x];
}

// 8 edges/thread: batch loads, 8 independent random rowptr reads, 8 scatters.
__global__ __launch_bounds__(256) void k_fill(const int* __restrict__ src,
                                              const int* __restrict__ dst,
                                              const int* __restrict__ rowptr,
                                              const int* __restrict__ rank,
                                              int* __restrict__ csr, int E) {
    int base = (blockIdx.x * 256 + threadIdx.x) * 8;
    if (base + 8 <= E) {
        int4 d0 = *(const int4*)(dst + base);
        int4 d1 = *(const int4*)(dst + base + 4);
        int4 s0 = *(const int4*)(src + base);
        int4 s1 = *(const int4*)(src + base + 4);
        int4 r0 = *(const int4*)(rank + base);
        int4 r1 = *(const int4*)(rank + base + 4);
        int p0 = rowptr[d0.x], p1 = rowptr[d0.y], p2 = rowptr[d0.z], p3 = rowptr[d0.w];
        int p4 = rowptr[d1.x], p5 = rowptr[d1.y], p6 = rowptr[d1.z], p7 = rowptr[d1.w];
        csr[p0 + r0.x] = s0.x;
        csr[p1 + r0.y] = s0.y;
        csr[p2 + r0.z] = s0.z;
        csr[p3 + r0.w] = s0.w;
        csr[p4 + r1.x] = s1.x;
        csr[p5 + r1.y] = s1.y;
        csr[p6 + r1.z] = s1.z;
        csr[p7 + r1.w] = s1.w;
    } else {
        for (int e = base; e < E; ++e) csr[rowptr[dst[e]] + rank[e]] = src[e];
    }
}

// ---------------- weight pack into MFMA B-fragment order ----------------
__global__ __launch_bounds__(256) void k_pack(const float* __restrict__ WA,
                                              const float* __restrict__ WB,
                                              int CA, int NC,
                                              unsigned short* __restrict__ Wp) {
    int tid = blockIdx.x * 256 + threadIdx.x;
    if (tid >= NC * 16) return;
    int lane = tid & 63, kk = (tid >> 6) & 3, tg = tid >> 8;
    int l15 = lane & 15, quad = lane >> 4;
    int c = tg * 16 + l15;
    const float* W = (c < CA) ? WA : WB;
    int cc = (c < CA) ? c : c - CA;
    short8 v;
    #pragma unroll
    for (int j = 0; j < 8; ++j) {
        int k = kk * 32 + quad * 8 + j;
        v[j] = (short)f2bf(W[(size_t)k * CA + cc]);
    }
    *(short8*)(Wp + (size_t)tid * 8) = v;
}

// ---------------- MFMA GEMM: Y[N x NC] = A[N x 128] @ W ----------------
template<int T, bool ABF16>
__global__ __launch_bounds__(256) void k_gemm(const void* __restrict__ Xv,
                                              const unsigned short* __restrict__ Wp,
                                              unsigned short* __restrict__ Y,
                                              int Nrows, int NC) {
    const int t = threadIdx.x;
    const int wave = t >> 6, lane = t & 63;
    const int quad = lane >> 4, l15 = lane & 15;
    const int row0 = blockIdx.x * 32;
    const int c0w = wave * (T * 16);

    f32x4 acc[2][T];
    #pragma unroll
    for (int mt = 0; mt < 2; ++mt)
        #pragma unroll
        for (int tt = 0; tt < T; ++tt) acc[mt][tt] = (f32x4){0.f, 0.f, 0.f, 0.f};

    #pragma unroll
    for (int kk = 0; kk < 4; ++kk) {
        const int k0 = kk * 32 + quad * 8;
        short8 a[2];
        #pragma unroll
        for (int mt = 0; mt < 2; ++mt) {
            int row = row0 + mt * 16 + l15;
            if (row > Nrows - 1) row = Nrows - 1;
            if (ABF16) {
                a[mt] = *(const short8*)((const unsigned short*)Xv + (size_t)row * 128 + k0);
            } else {
                const float* xp = (const float*)Xv + (size_t)row * 128 + k0;
                float4 f0 = *(const float4*)xp;
                float4 f1 = *(const float4*)(xp + 4);
                short8 v;
                v[0] = (short)f2bf(f0.x); v[1] = (short)f2bf(f0.y);
                v[2] = (short)f2bf(f0.z); v[3] = (short)f2bf(f0.w);
                v[4] = (short)f2bf(f1.x); v[5] = (short)f2bf(f1.y);
                v[6] = (short)f2bf(f1.z); v[7] = (short)f2bf(f1.w);
                a[mt] = v;
            }
        }
        short8 b[T];
        #pragma unroll
        for (int tt = 0; tt < T; ++tt) {
            int tg = (c0w >> 4) + tt;
            b[tt] = *(const short8*)(Wp + ((size_t)(tg * 4 + kk) * 64 + lane) * 8);
        }
        #pragma unroll
        for (int mt = 0; mt < 2; ++mt)
            #pragma unroll
            for (int tt = 0; tt < T; ++tt)
                acc[mt][tt] = __builtin_amdgcn_mfma_f32_16x16x32_bf16(
                    a[mt], b[tt], acc[mt][tt], 0, 0, 0);
    }

    #pragma unroll
    for (int mt = 0; mt < 2; ++mt) {
        #pragma unroll
        for (int r = 0; r < 4; ++r) {
            int row = row0 + mt * 16 + quad * 4 + r;
            if (row < Nrows) {
                #pragma unroll
                for (int tt = 0; tt < T; ++tt)
                    Y[(size_t)row * NC + c0w + tt * 16 + l15] = f2bf(acc[mt][tt][r]);
            }
        }
    }
}

// ---------------- aggregation ----------------
// agg0: wave per node, 4 neighbors in flight (16 lanes x 16B each), 2x unroll.
__global__ __launch_bounds__(256) void k_agg0(const unsigned short* __restrict__ Y0,
                                              const int* __restrict__ deg,
                                              const int* __restrict__ rowptr,
                                              const int* __restrict__ csr,
                                              const float* __restrict__ bl0,
                                              unsigned short* __restrict__ h, int Nn) {
    int wave = threadIdx.x >> 6, lane = threadIdx.x & 63;
    int n = blockIdx.x * 4 + wave;
    if (n >= Nn) return;
    int g = lane >> 4, l15 = lane & 15;
    int dg = deg[n], st = rowptr[n];
    float acc[8] = {};
    int e = 0;
    for (; e + 8 <= dg; e += 8) {
        int s0 = csr[st + e + g];
        int s1 = csr[st + e + 4 + g];
        short8 v0 = *(const short8*)(Y0 + (size_t)s0 * 256 + l15 * 8);
        short8 v1 = *(const short8*)(Y0 + (size_t)s1 * 256 + l15 * 8);
        #pragma unroll
        for (int j = 0; j < 8; ++j) acc[j] += bf2f_s(v0[j]) + bf2f_s(v1[j]);
    }
    for (; e + 4 <= dg; e += 4) {
        int s0 = csr[st + e + g];
        short8 v0 = *(const short8*)(Y0 + (size_t)s0 * 256 + l15 * 8);
        #pragma unroll
        for (int j = 0; j < 8; ++j) acc[j] += bf2f_s(v0[j]);
    }
    if (e + g < dg) {
        int s0 = csr[st + e + g];
        short8 v0 = *(const short8*)(Y0 + (size_t)s0 * 256 + l15 * 8);
        #pragma unroll
        for (int j = 0; j < 8; ++j) acc[j] += bf2f_s(v0[j]);
    }
    #pragma unroll
    for (int j = 0; j < 8; ++j) {
        acc[j] += __shfl_xor(acc[j], 16);
        acc[j] += __shfl_xor(acc[j], 32);
    }
    if (lane < 16) {   // quad 0 writes elements [l15*8, l15*8+8)
        float inv = 1.f / fmaxf((float)dg, 1.f);
        short8 rt = *(const short8*)(Y0 + (size_t)n * 256 + 128 + l15 * 8);
        float4 b0 = *(const float4*)(bl0 + l15 * 8);
        float4 b1 = *(const float4*)(bl0 + l15 * 8 + 4);
        const float* bb[2] = {(const float*)&b0, (const float*)&b1};
        short8 o;
        #pragma unroll
        for (int j = 0; j < 8; ++j) {
            float v = fmaxf(acc[j] * inv + bb[j >> 2][j & 3] + bf2f_s(rt[j]), 0.f);
            o[j] = (short)f2bf(v);
        }
        *(short8*)(h + (size_t)n * 128 + l15 * 8) = o;
    }
}

// agg1: wave per node, 8 neighbors in flight (8 lanes x 16B each), 2x unroll.
__global__ __launch_bounds__(256) void k_agg1(const unsigned short* __restrict__ Y1,
                                              const int* __restrict__ deg,
                                              const int* __restrict__ rowptr,
                                              const int* __restrict__ csr,
                                              const float* __restrict__ bl1,
                                              float* __restrict__ out, int Nn) {
    int wave = threadIdx.x >> 6, lane = threadIdx.x & 63;
    int n = blockIdx.x * 4 + wave;
    if (n >= Nn) return;
    int g = lane >> 3, l7 = lane & 7;
    int dg = deg[n], st = rowptr[n];
    float acc[8] = {};
    int e = 0;
    for (; e + 16 <= dg; e += 16) {
        int s0 = csr[st + e + g];
        int s1 = csr[st + e + 8 + g];
        short8 v0 = *(const short8*)(Y1 + (size_t)s0 * 128 + l7 * 8);
        short8 v1 = *(const short8*)(Y1 + (size_t)s1 * 128 + l7 * 8);
        #pragma unroll
        for (int j = 0; j < 8; ++j) acc[j] += bf2f_s(v0[j]) + bf2f_s(v1[j]);
    }
    for (; e + 8 <= dg; e += 8) {
        int s0 = csr[st + e + g];
        short8 v0 = *(const short8*)(Y1 + (size_t)s0 * 128 + l7 * 8);
        #pragma unroll
        for (int j = 0; j < 8; ++j) acc[j] += bf2f_s(v0[j]);
    }
    if (e + g < dg) {
        int s0 = csr[st + e + g];
        short8 v0 = *(const short8*)(Y1 + (size_t)s0 * 128 + l7 * 8);
        #pragma unroll
        for (int j = 0; j < 8; ++j) acc[j] += bf2f_s(v0[j]);
    }
    #pragma unroll
    for (int j = 0; j < 8; ++j) {
        acc[j] += __shfl_xor(acc[j], 8);
        acc[j] += __shfl_xor(acc[j], 16);
        acc[j] += __shfl_xor(acc[j], 32);
    }
    if (lane < 8) {    // elements [l7*8, l7*8+8)
        float inv = 1.f / fmaxf((float)dg, 1.f);
        short8 rt = *(const short8*)(Y1 + (size_t)n * 128 + 64 + l7 * 8);
        float4 b0 = *(const float4*)(bl1 + l7 * 8);
        float4 b1 = *(const float4*)(bl1 + l7 * 8 + 4);
        const float* bb[2] = {(const float*)&b0, (const float*)&b1};
        float4 o0, o1;
        float* oo[2] = {(float*)&o0, (float*)&o1};
        #pragma unroll
        for (int j = 0; j < 8; ++j)
            oo[j >> 2][j & 3] = acc[j] * inv + bb[j >> 2][j & 3] + bf2f_s(rt[j]);
        *(float4*)(out + (size_t)n * 64 + l7 * 8) = o0;
        *(float4*)(out + (size_t)n * 64 + l7 * 8 + 4) = o1;
    }
}

extern "C" void kernel_launch(void* const* d_in, const int* in_sizes, int n_in,
                              void* d_out, int out_size, void* d_ws, size_t ws_size,
                              hipStream_t stream) {
    const float* x   = (const float*)d_in[0];
    const int* eidx  = (const int*)d_in[1];
    const float* Wl0 = (const float*)d_in[2];
    const float* bl0 = (const float*)d_in[3];
    const float* Wr0 = (const float*)d_in[4];
    const float* Wl1 = (const float*)d_in[5];
    const float* bl1 = (const float*)d_in[6];
    const float* Wr1 = (const float*)d_in[7];
    float* out = (float*)d_out;

    const int N = in_sizes[0] / 128;   // 100000
    const int E = in_sizes[1] / 2;     // 1600000
    const int* src = eidx;
    const int* dst = eidx + E;

    // workspace layout
    int* deg    = (int*)d_ws;                      // N
    int* rowptr = deg + N;                         // N
    int* bsum   = rowptr + N;                      // 512
    int* csr    = bsum + 512;                      // E
    unsigned short* Wp0 = (unsigned short*)(csr + E);   // 256*16*8
    unsigned short* Wp1 = Wp0 + 32768;                  // 128*16*8
    unsigned short* Y0  = Wp1 + 16384;                  // N*256 bf16
    unsigned short* h   = Y0 + (size_t)N * 256;         // N*128 bf16
    unsigned short* Y1  = Y0;                           // reuse Y0
    int* rank = (int*)Y0;   // E ints; consumed by k_fill BEFORE gemm0 writes Y0

    hipMemsetAsync(deg, 0, (size_t)N * sizeof(int), stream);

    int ebl8 = (E + 2047) / 2048;   // 8 edges per thread
    int nb  = (N + 255) / 256;
    k_degree<<<ebl8, 256, 0, stream>>>(dst, deg, rank, E);
    k_scan1<<<nb, 256, 0, stream>>>(deg, rowptr, bsum, N);
    k_scan2<<<1, 512, 0, stream>>>(bsum, nb);
    k_scan3<<<nb, 256, 0, stream>>>(rowptr, bsum, N);
    k_fill<<<ebl8, 256, 0, stream>>>(src, dst, rowptr, rank, csr, E);

    k_pack<<<(256 * 16 + 255) / 256, 256, 0, stream>>>(Wl0, Wr0, 128, 256, Wp0);
    k_pack<<<(128 * 16 + 255) / 256, 256, 0, stream>>>(Wl1, Wr1, 64, 128, Wp1);

    int gbl = (N + 31) / 32;
    k_gemm<4, false><<<gbl, 256, 0, stream>>>((const void*)x, Wp0, Y0, N, 256);
    k_agg0<<<(N + 3) / 4, 256, 0, stream>>>(Y0, deg, rowptr, csr, bl0, h, N);
    k_gemm<2, true><<<gbl, 256, 0, stream>>>((const void*)h, Wp1, Y1, N, 128);
    k_agg1<<<(N + 3) / 4, 256, 0, stream>>>(Y1, deg, rowptr, csr, bl1, out, N);
}

// Round 5
// 350.530 us; speedup vs baseline: 1.0606x; 1.0606x over previous
//
#include <hip/hip_runtime.h>

// GraphSAGE 2-layer, N=100000, IN=HID=128, OUT=64, E=1.6M, fp32 in/out.
//   agg @ Wl == segsum((h@Wl)[src])/cnt  -> GEMM first, then gather-mean.
//   Intermediates bf16; GEMMs bf16 MFMA 16x16x32 fp32-accum.
// Round 5: CSR build rebuilt around bucketing to dodge the ~23G/s device-atomic
// ceiling (R4 evidence: throughput flat vs occupancy/unroll):
//   fused [GEMM0 | bucket-scatter]: blocks<3125 compute Y0 = x@[Wl0|Wr0];
//     remaining 196 blocks bucket edges by dst>>7 with LDS histograms and
//     ~153K chunk-reservation atomics (was 1.6M returning atomics).
//   k_bscan: exclusive scan of 782 bucket counts (1 block).
//   k_csr: block-per-bucket: LDS hist(128 dst) -> scan -> rowptr + csr
//     (contiguous writes). deg[] gone: dg = rowptr[n+1]-rowptr[n].

typedef short short8 __attribute__((ext_vector_type(8)));
typedef float f32x4 __attribute__((ext_vector_type(4)));

#define NBUCK 782      // ceil(100000 / 128)
#define BCAP  3072     // per-bucket region capacity (avg 2046, sigma 45)
#define EPB   8192     // edges per bucket-build block (256 thr x 32)

static __device__ __forceinline__ unsigned short f2bf(float f) {
    union { float f; unsigned u; } c; c.f = f;
    unsigned u = c.u + 0x7fffu + ((c.u >> 16) & 1u);   // RNE
    return (unsigned short)(u >> 16);
}
static __device__ __forceinline__ float bf2f(unsigned short b) {
    union { unsigned u; float f; } c; c.u = ((unsigned)b) << 16;
    return c.f;
}
static __device__ __forceinline__ float bf2f_s(short b) {
    return bf2f((unsigned short)b);
}

// ---------------- weight pack into MFMA B-fragment order ----------------
__global__ __launch_bounds__(256) void k_pack(const float* __restrict__ WA,
                                              const float* __restrict__ WB,
                                              int CA, int NC,
                                              unsigned short* __restrict__ Wp) {
    int tid = blockIdx.x * 256 + threadIdx.x;
    if (tid >= NC * 16) return;
    int lane = tid & 63, kk = (tid >> 6) & 3, tg = tid >> 8;
    int l15 = lane & 15, quad = lane >> 4;
    int c = tg * 16 + l15;
    const float* W = (c < CA) ? WA : WB;
    int cc = (c < CA) ? c : c - CA;
    short8 v;
    #pragma unroll
    for (int j = 0; j < 8; ++j) {
        int k = kk * 32 + quad * 8 + j;
        v[j] = (short)f2bf(W[(size_t)k * CA + cc]);
    }
    *(short8*)(Wp + (size_t)tid * 8) = v;
}

// ---------------- fused: GEMM0 (blocks < gemmBlocks) | bucket scatter ----------------
__global__ __launch_bounds__(256) void k_gemm0_bucket(
        const float* __restrict__ X, const unsigned short* __restrict__ Wp,
        unsigned short* __restrict__ Y, int Nrows,
        const int* __restrict__ src, const int* __restrict__ dst,
        int* __restrict__ cursor, int* __restrict__ bregion,
        int E, int gemmBlocks) {
    const int t = threadIdx.x;
    if ((int)blockIdx.x < gemmBlocks) {
        // ---- GEMM path: Y[N x 256] = X[N x 128] @ W, T=4 col-tiles/wave ----
        const int wave = t >> 6, lane = t & 63;
        const int quad = lane >> 4, l15 = lane & 15;
        const int row0 = blockIdx.x * 32;
        const int c0w = wave * 64;
        f32x4 acc[2][4];
        #pragma unroll
        for (int mt = 0; mt < 2; ++mt)
            #pragma unroll
            for (int tt = 0; tt < 4; ++tt) acc[mt][tt] = (f32x4){0.f, 0.f, 0.f, 0.f};
        #pragma unroll
        for (int kk = 0; kk < 4; ++kk) {
            const int k0 = kk * 32 + quad * 8;
            short8 a[2];
            #pragma unroll
            for (int mt = 0; mt < 2; ++mt) {
                int row = row0 + mt * 16 + l15;
                if (row > Nrows - 1) row = Nrows - 1;
                const float* xp = X + (size_t)row * 128 + k0;
                float4 f0 = *(const float4*)xp;
                float4 f1 = *(const float4*)(xp + 4);
                short8 v;
                v[0] = (short)f2bf(f0.x); v[1] = (short)f2bf(f0.y);
                v[2] = (short)f2bf(f0.z); v[3] = (short)f2bf(f0.w);
                v[4] = (short)f2bf(f1.x); v[5] = (short)f2bf(f1.y);
                v[6] = (short)f2bf(f1.z); v[7] = (short)f2bf(f1.w);
                a[mt] = v;
            }
            short8 b[4];
            #pragma unroll
            for (int tt = 0; tt < 4; ++tt) {
                int tg = (c0w >> 4) + tt;
                b[tt] = *(const short8*)(Wp + ((size_t)(tg * 4 + kk) * 64 + lane) * 8);
            }
            #pragma unroll
            for (int mt = 0; mt < 2; ++mt)
                #pragma unroll
                for (int tt = 0; tt < 4; ++tt)
                    acc[mt][tt] = __builtin_amdgcn_mfma_f32_16x16x32_bf16(
                        a[mt], b[tt], acc[mt][tt], 0, 0, 0);
        }
        #pragma unroll
        for (int mt = 0; mt < 2; ++mt)
            #pragma unroll
            for (int r = 0; r < 4; ++r) {
                int row = row0 + mt * 16 + quad * 4 + r;
                if (row < Nrows) {
                    #pragma unroll
                    for (int tt = 0; tt < 4; ++tt)
                        Y[(size_t)row * 256 + c0w + tt * 16 + l15] = f2bf(acc[mt][tt][r]);
                }
            }
        return;
    }
    // ---- bucket path ----
    __shared__ int hist[NBUCK];
    __shared__ int basel[NBUCK];
    int bid = blockIdx.x - gemmBlocks;
    for (int i = t; i < NBUCK; i += 256) hist[i] = 0;
    __syncthreads();
    int e0 = bid * EPB + t * 32;
    int d[32];
    if (e0 + 32 <= E) {
        #pragma unroll
        for (int q = 0; q < 8; ++q) {
            int4 v = *(const int4*)(dst + e0 + q * 4);
            d[q * 4 + 0] = v.x; d[q * 4 + 1] = v.y;
            d[q * 4 + 2] = v.z; d[q * 4 + 3] = v.w;
        }
    } else {
        #pragma unroll
        for (int j = 0; j < 32; ++j) d[j] = (e0 + j < E) ? dst[e0 + j] : -1;
    }
    #pragma unroll
    for (int j = 0; j < 32; ++j)
        if (d[j] >= 0) atomicAdd(&hist[d[j] >> 7], 1);
    __syncthreads();
    for (int i = t; i < NBUCK; i += 256) {
        int c = hist[i];
        basel[i] = (c > 0) ? atomicAdd(&cursor[i], c) : 0;
    }
    __syncthreads();
    for (int i = t; i < NBUCK; i += 256) hist[i] = 0;
    __syncthreads();
    int s[32];
    if (e0 + 32 <= E) {
        #pragma unroll
        for (int q = 0; q < 8; ++q) {
            int4 v = *(const int4*)(src + e0 + q * 4);
            s[q * 4 + 0] = v.x; s[q * 4 + 1] = v.y;
            s[q * 4 + 2] = v.z; s[q * 4 + 3] = v.w;
        }
    } else {
        #pragma unroll
        for (int j = 0; j < 32; ++j) s[j] = (e0 + j < E) ? src[e0 + j] : 0;
    }
    #pragma unroll
    for (int j = 0; j < 32; ++j) {
        if (d[j] < 0) continue;
        int b = d[j] >> 7;
        int r = atomicAdd(&hist[b], 1);          // LDS atomic: rank within block chunk
        bregion[(size_t)b * BCAP + basel[b] + r] = s[j] | ((d[j] & 127) << 20);
    }
}

// ---------------- exclusive scan of bucket counts (1 block) ----------------
__global__ __launch_bounds__(1024) void k_bscan(const int* __restrict__ cursor,
                                                int* __restrict__ bbase) {
    __shared__ int sm[1024];
    int t = threadIdx.x;
    int v = (t < NBUCK) ? cursor[t] : 0;
    sm[t] = v;
    __syncthreads();
    #pragma unroll
    for (int off = 1; off < 1024; off <<= 1) {
        int x = (t >= off) ? sm[t - off] : 0;
        __syncthreads();
        sm[t] += x;
        __syncthreads();
    }
    if (t < NBUCK) bbase[t] = sm[t] - v;
}

// ---------------- finalize: block per bucket -> rowptr + csr ----------------
__global__ __launch_bounds__(256) void k_csr(const int* __restrict__ cursor,
                                             const int* __restrict__ bbase,
                                             const int* __restrict__ bregion,
                                             int* __restrict__ rowptr,
                                             int* __restrict__ csr, int Nn) {
    __shared__ int words[BCAP];
    __shared__ int hist[128], sc[128], rank[128];
    int b = blockIdx.x, t = threadIdx.x;
    int cnt = cursor[b], gbase = bbase[b];
    if (t < 128) { hist[t] = 0; rank[t] = 0; }
    __syncthreads();
    for (int i = t; i < cnt; i += 256) {
        int w = bregion[(size_t)b * BCAP + i];
        words[i] = w;
        atomicAdd(&hist[w >> 20], 1);
    }
    __syncthreads();
    if (t < 128) sc[t] = hist[t];
    __syncthreads();
    #pragma unroll
    for (int off = 1; off < 128; off <<= 1) {
        int x = 0;
        if (t < 128 && t >= off) x = sc[t - off];
        __syncthreads();
        if (t < 128) sc[t] += x;
        __syncthreads();
    }
    if (t < 128) sc[t] -= hist[t];   // exclusive
    __syncthreads();
    if (t < 128) {
        int node = b * 128 + t;
        if (node <= Nn) rowptr[node] = gbase + sc[t];
    }
    for (int i = t; i < cnt; i += 256) {
        int w = words[i];
        int d7 = w >> 20;
        int r = atomicAdd(&rank[d7], 1);
        csr[gbase + sc[d7] + r] = w & 0xFFFFF;
    }
}

// ---------------- MFMA GEMM (layer 1): Y[N x 128] = A_bf16[N x 128] @ W ----------------
__global__ __launch_bounds__(256) void k_gemm1(const unsigned short* __restrict__ Xv,
                                               const unsigned short* __restrict__ Wp,
                                               unsigned short* __restrict__ Y,
                                               int Nrows) {
    const int t = threadIdx.x;
    const int wave = t >> 6, lane = t & 63;
    const int quad = lane >> 4, l15 = lane & 15;
    const int row0 = blockIdx.x * 32;
    const int c0w = wave * 32;
    f32x4 acc[2][2];
    #pragma unroll
    for (int mt = 0; mt < 2; ++mt)
        #pragma unroll
        for (int tt = 0; tt < 2; ++tt) acc[mt][tt] = (f32x4){0.f, 0.f, 0.f, 0.f};
    #pragma unroll
    for (int kk = 0; kk < 4; ++kk) {
        const int k0 = kk * 32 + quad * 8;
        short8 a[2];
        #pragma unroll
        for (int mt = 0; mt < 2; ++mt) {
            int row = row0 + mt * 16 + l15;
            if (row > Nrows - 1) row = Nrows - 1;
            a[mt] = *(const short8*)(Xv + (size_t)row * 128 + k0);
        }
        short8 b[2];
        #pragma unroll
        for (int tt = 0; tt < 2; ++tt) {
            int tg = (c0w >> 4) + tt;
            b[tt] = *(const short8*)(Wp + ((size_t)(tg * 4 + kk) * 64 + lane) * 8);
        }
        #pragma unroll
        for (int mt = 0; mt < 2; ++mt)
            #pragma unroll
            for (int tt = 0; tt < 2; ++tt)
                acc[mt][tt] = __builtin_amdgcn_mfma_f32_16x16x32_bf16(
                    a[mt], b[tt], acc[mt][tt], 0, 0, 0);
    }
    #pragma unroll
    for (int mt = 0; mt < 2; ++mt)
        #pragma unroll
        for (int r = 0; r < 4; ++r) {
            int row = row0 + mt * 16 + quad * 4 + r;
            if (row < Nrows) {
                #pragma unroll
                for (int tt = 0; tt < 2; ++tt)
                    Y[(size_t)row * 128 + c0w + tt * 16 + l15] = f2bf(acc[mt][tt][r]);
            }
        }
}

// ---------------- aggregation ----------------
// agg0: wave per node, 4 nbrs per load (16 lanes x 16B), 2x unroll.
__global__ __launch_bounds__(256) void k_agg0(const unsigned short* __restrict__ Y0,
                                              const int* __restrict__ rowptr,
                                              const int* __restrict__ csr,
                                              const float* __restrict__ bl0,
                                              unsigned short* __restrict__ h, int Nn) {
    int wave = threadIdx.x >> 6, lane = threadIdx.x & 63;
    int n = blockIdx.x * 4 + wave;
    if (n >= Nn) return;
    int g = lane >> 4, l15 = lane & 15;
    int st = rowptr[n], dg = rowptr[n + 1] - st;
    float acc[8] = {};
    int e = 0;
    for (; e + 8 <= dg; e += 8) {
        int s0 = csr[st + e + g];
        int s1 = csr[st + e + 4 + g];
        short8 v0 = *(const short8*)(Y0 + (size_t)s0 * 256 + l15 * 8);
        short8 v1 = *(const short8*)(Y0 + (size_t)s1 * 256 + l15 * 8);
        #pragma unroll
        for (int j = 0; j < 8; ++j) acc[j] += bf2f_s(v0[j]) + bf2f_s(v1[j]);
    }
    for (; e + 4 <= dg; e += 4) {
        int s0 = csr[st + e + g];
        short8 v0 = *(const short8*)(Y0 + (size_t)s0 * 256 + l15 * 8);
        #pragma unroll
        for (int j = 0; j < 8; ++j) acc[j] += bf2f_s(v0[j]);
    }
    if (e + g < dg) {
        int s0 = csr[st + e + g];
        short8 v0 = *(const short8*)(Y0 + (size_t)s0 * 256 + l15 * 8);
        #pragma unroll
        for (int j = 0; j < 8; ++j) acc[j] += bf2f_s(v0[j]);
    }
    #pragma unroll
    for (int j = 0; j < 8; ++j) {
        acc[j] += __shfl_xor(acc[j], 16);
        acc[j] += __shfl_xor(acc[j], 32);
    }
    if (lane < 16) {
        float inv = 1.f / fmaxf((float)dg, 1.f);
        short8 rt = *(const short8*)(Y0 + (size_t)n * 256 + 128 + l15 * 8);
        float4 b0 = *(const float4*)(bl0 + l15 * 8);
        float4 b1 = *(const float4*)(bl0 + l15 * 8 + 4);
        const float* bb[2] = {(const float*)&b0, (const float*)&b1};
        short8 o;
        #pragma unroll
        for (int j = 0; j < 8; ++j) {
            float v = fmaxf(acc[j] * inv + bb[j >> 2][j & 3] + bf2f_s(rt[j]), 0.f);
            o[j] = (short)f2bf(v);
        }
        *(short8*)(h + (size_t)n * 128 + l15 * 8) = o;
    }
}

// agg1: wave per node, 8 nbrs per load (8 lanes x 16B), 2x unroll.
__global__ __launch_bounds__(256) void k_agg1(const unsigned short* __restrict__ Y1,
                                              const int* __restrict__ rowptr,
                                              const int* __restrict__ csr,
                                              const float* __restrict__ bl1,
                                              float* __restrict__ out, int Nn) {
    int wave = threadIdx.x >> 6, lane = threadIdx.x & 63;
    int n = blockIdx.x * 4 + wave;
    if (n >= Nn) return;
    int g = lane >> 3, l7 = lane & 7;
    int st = rowptr[n], dg = rowptr[n + 1] - st;
    float acc[8] = {};
    int e = 0;
    for (; e + 16 <= dg; e += 16) {
        int s0 = csr[st + e + g];
        int s1 = csr[st + e + 8 + g];
        short8 v0 = *(const short8*)(Y1 + (size_t)s0 * 128 + l7 * 8);
        short8 v1 = *(const short8*)(Y1 + (size_t)s1 * 128 + l7 * 8);
        #pragma unroll
        for (int j = 0; j < 8; ++j) acc[j] += bf2f_s(v0[j]) + bf2f_s(v1[j]);
    }
    for (; e + 8 <= dg; e += 8) {
        int s0 = csr[st + e + g];
        short8 v0 = *(const short8*)(Y1 + (size_t)s0 * 128 + l7 * 8);
        #pragma unroll
        for (int j = 0; j < 8; ++j) acc[j] += bf2f_s(v0[j]);
    }
    if (e + g < dg) {
        int s0 = csr[st + e + g];
        short8 v0 = *(const short8*)(Y1 + (size_t)s0 * 128 + l7 * 8);
        #pragma unroll
        for (int j = 0; j < 8; ++j) acc[j] += bf2f_s(v0[j]);
    }
    #pragma unroll
    for (int j = 0; j < 8; ++j) {
        acc[j] += __shfl_xor(acc[j], 8);
        acc[j] += __shfl_xor(acc[j], 16);
        acc[j] += __shfl_xor(acc[j], 32);
    }
    if (lane < 8) {
        float inv = 1.f / fmaxf((float)dg, 1.f);
        short8 rt = *(const short8*)(Y1 + (size_t)n * 128 + 64 + l7 * 8);
        float4 b0 = *(const float4*)(bl1 + l7 * 8);
        float4 b1 = *(const float4*)(bl1 + l7 * 8 + 4);
        const float* bb[2] = {(const float*)&b0, (const float*)&b1};
        float4 o0, o1;
        float* oo[2] = {(float*)&o0, (float*)&o1};
        #pragma unroll
        for (int j = 0; j < 8; ++j)
            oo[j >> 2][j & 3] = acc[j] * inv + bb[j >> 2][j & 3] + bf2f_s(rt[j]);
        *(float4*)(out + (size_t)n * 64 + l7 * 8) = o0;
        *(float4*)(out + (size_t)n * 64 + l7 * 8 + 4) = o1;
    }
}

extern "C" void kernel_launch(void* const* d_in, const int* in_sizes, int n_in,
                              void* d_out, int out_size, void* d_ws, size_t ws_size,
                              hipStream_t stream) {
    const float* x   = (const float*)d_in[0];
    const int* eidx  = (const int*)d_in[1];
    const float* Wl0 = (const float*)d_in[2];
    const float* bl0 = (const float*)d_in[3];
    const float* Wr0 = (const float*)d_in[4];
    const float* Wl1 = (const float*)d_in[5];
    const float* bl1 = (const float*)d_in[6];
    const float* Wr1 = (const float*)d_in[7];
    float* out = (float*)d_out;

    const int N = in_sizes[0] / 128;   // 100000
    const int E = in_sizes[1] / 2;     // 1600000
    const int* src = eidx;
    const int* dst = eidx + E;

    // workspace layout (all sections 16B aligned)
    int* rowptr  = (int*)d_ws;                          // N+1 (pad to N+4)
    int* cursor  = rowptr + (N + 4);                    // NBUCK (pad 784)
    int* bbase   = cursor + 784;                        // NBUCK (pad 784)
    int* bregion = bbase + 784;                         // NBUCK*BCAP
    int* csr     = bregion + (size_t)NBUCK * BCAP;      // E
    unsigned short* Wp0 = (unsigned short*)(csr + E);   // 256*16*8
    unsigned short* Wp1 = Wp0 + 32768;                  // 128*16*8
    unsigned short* Y0  = Wp1 + 16384;                  // N*256 bf16
    unsigned short* h   = Y0 + (size_t)N * 256;         // N*128 bf16
    unsigned short* Y1  = Y0;                           // reuse Y0

    hipMemsetAsync(cursor, 0, NBUCK * sizeof(int), stream);

    k_pack<<<(256 * 16 + 255) / 256, 256, 0, stream>>>(Wl0, Wr0, 128, 256, Wp0);
    k_pack<<<(128 * 16 + 255) / 256, 256, 0, stream>>>(Wl1, Wr1, 64, 128, Wp1);

    int gemmBlocks = (N + 31) / 32;               // 3125
    int nbb = (E + EPB - 1) / EPB;                // 196
    k_gemm0_bucket<<<gemmBlocks + nbb, 256, 0, stream>>>(
        x, Wp0, Y0, N, src, dst, cursor, bregion, E, gemmBlocks);
    k_bscan<<<1, 1024, 0, stream>>>(cursor, bbase);
    k_csr<<<NBUCK, 256, 0, stream>>>(cursor, bbase, bregion, rowptr, csr, N);

    k_agg0<<<(N + 3) / 4, 256, 0, stream>>>(Y0, rowptr, csr, bl0, h, N);
    k_gemm1<<<(N + 31) / 32, 256, 0, stream>>>(h, Wp1, Y1, N);
    k_agg1<<<(N + 3) / 4, 256, 0, stream>>>(Y1, rowptr, csr, bl1, out, N);
}

// Round 6
// 327.654 us; speedup vs baseline: 1.1347x; 1.0698x over previous
//
#include <hip/hip_runtime.h>

// GraphSAGE 2-layer, N=100000, IN=HID=128, OUT=64, E=1.6M, fp32 in/out.
//   agg @ Wl == segsum((h@Wl)[src])/cnt  -> GEMM first, then gather-mean.
// Round 6: gathered halves stored fp8 e4m3 (P0: N x 128 fp8, P1: N x 64 fp8),
//   root halves bf16 (Q0, Q1). Halves the dominant random-gather HBM traffic.
//   Decode: v_cvt_pk_f32_fp8 if available, else exact bit-trick (<<20, *2^120).
//   k_bscan folded into k_csr (per-block prefix over 782 bucket counts).

typedef short short8 __attribute__((ext_vector_type(8)));
typedef float f32x4 __attribute__((ext_vector_type(4)));
typedef float f32x2 __attribute__((ext_vector_type(2)));

#define NBUCK 782      // ceil(100000 / 128)
#define BCAP  3072     // per-bucket region capacity (avg 2046, sigma 45)
#define EPB   8192     // edges per bucket-build block (256 thr x 32)

static __device__ __forceinline__ unsigned short f2bf(float f) {
    union { float f; unsigned u; } c; c.f = f;
    unsigned u = c.u + 0x7fffu + ((c.u >> 16) & 1u);   // RNE
    return (unsigned short)(u >> 16);
}
static __device__ __forceinline__ float bf2f(unsigned short b) {
    union { unsigned u; float f; } c; c.u = ((unsigned)b) << 16;
    return c.f;
}
static __device__ __forceinline__ float bf2f_s(short b) {
    return bf2f((unsigned short)b);
}

// fp8 e4m3fn (OCP) software encode, RNE, exact subnormals, clamp to 448.
static __device__ __forceinline__ unsigned char f2fp8(float x) {
    union { float f; unsigned u; } c; c.f = x;
    unsigned s = (c.u >> 24) & 0x80u;
    float a = __builtin_fabsf(x);
    if (a < 0.015625f) {                        // subnormal: m = RNE(a*512)
        int m = (int)rintf(a * 512.0f);         // 0..8 (8 carries to 2^-6)
        return (unsigned char)(s | (unsigned)m);
    }
    unsigned u = c.u + 0x7ffffu + ((c.u >> 20) & 1u);
    int e = (int)((u >> 23) & 0xff) - 120;      // e4m3 biased exponent
    unsigned m = (u >> 20) & 7u;
    if (e > 15) { e = 15; m = 6; }              // clamp to 448, never NaN
    return (unsigned char)(s | (unsigned)(e << 3) | m);
}

// decode 4 fp8 from one dword, accumulate into a[0..3]
static __device__ __forceinline__ void acc_fp8x4(unsigned w, float* a) {
#if __has_builtin(__builtin_amdgcn_cvt_pk_f32_fp8)
    f32x2 lo = __builtin_amdgcn_cvt_pk_f32_fp8((int)w, false);
    f32x2 hi = __builtin_amdgcn_cvt_pk_f32_fp8((int)w, true);
    a[0] += lo[0]; a[1] += lo[1]; a[2] += hi[0]; a[3] += hi[1];
#else
    #pragma unroll
    for (int j = 0; j < 4; ++j) {
        unsigned b = (w >> (8 * j)) & 0xffu;
        union { unsigned u; float f; } c;
        c.u = ((b & 0x80u) << 24) | ((b & 0x7fu) << 20);
        a[j] += c.f * 0x1p120f;                 // exact for all e4m3fn values
    }
#endif
}

// ---------------- weight pack into MFMA B-fragment order ----------------
__global__ __launch_bounds__(256) void k_pack(const float* __restrict__ WA,
                                              const float* __restrict__ WB,
                                              int CA, int NC,
                                              unsigned short* __restrict__ Wp) {
    int tid = blockIdx.x * 256 + threadIdx.x;
    if (tid >= NC * 16) return;
    int lane = tid & 63, kk = (tid >> 6) & 3, tg = tid >> 8;
    int l15 = lane & 15, quad = lane >> 4;
    int c = tg * 16 + l15;
    const float* W = (c < CA) ? WA : WB;
    int cc = (c < CA) ? c : c - CA;
    short8 v;
    #pragma unroll
    for (int j = 0; j < 8; ++j) {
        int k = kk * 32 + quad * 8 + j;
        v[j] = (short)f2bf(W[(size_t)k * CA + cc]);
    }
    *(short8*)(Wp + (size_t)tid * 8) = v;
}

// ---------------- fused: GEMM0 (blocks < gemmBlocks) | bucket scatter ----------------
__global__ __launch_bounds__(256) void k_gemm0_bucket(
        const float* __restrict__ X, const unsigned short* __restrict__ Wp,
        unsigned char* __restrict__ P0, unsigned short* __restrict__ Q0, int Nrows,
        const int* __restrict__ src, const int* __restrict__ dst,
        int* __restrict__ cursor, int* __restrict__ bregion,
        int E, int gemmBlocks) {
    const int t = threadIdx.x;
    if ((int)blockIdx.x < gemmBlocks) {
        const int wave = t >> 6, lane = t & 63;
        const int quad = lane >> 4, l15 = lane & 15;
        const int row0 = blockIdx.x * 32;
        const int c0w = wave * 64;
        f32x4 acc[2][4];
        #pragma unroll
        for (int mt = 0; mt < 2; ++mt)
            #pragma unroll
            for (int tt = 0; tt < 4; ++tt) acc[mt][tt] = (f32x4){0.f, 0.f, 0.f, 0.f};
        #pragma unroll
        for (int kk = 0; kk < 4; ++kk) {
            const int k0 = kk * 32 + quad * 8;
            short8 a[2];
            #pragma unroll
            for (int mt = 0; mt < 2; ++mt) {
                int row = row0 + mt * 16 + l15;
                if (row > Nrows - 1) row = Nrows - 1;
                const float* xp = X + (size_t)row * 128 + k0;
                float4 f0 = *(const float4*)xp;
                float4 f1 = *(const float4*)(xp + 4);
                short8 v;
                v[0] = (short)f2bf(f0.x); v[1] = (short)f2bf(f0.y);
                v[2] = (short)f2bf(f0.z); v[3] = (short)f2bf(f0.w);
                v[4] = (short)f2bf(f1.x); v[5] = (short)f2bf(f1.y);
                v[6] = (short)f2bf(f1.z); v[7] = (short)f2bf(f1.w);
                a[mt] = v;
            }
            short8 b[4];
            #pragma unroll
            for (int tt = 0; tt < 4; ++tt) {
                int tg = (c0w >> 4) + tt;
                b[tt] = *(const short8*)(Wp + ((size_t)(tg * 4 + kk) * 64 + lane) * 8);
            }
            #pragma unroll
            for (int mt = 0; mt < 2; ++mt)
                #pragma unroll
                for (int tt = 0; tt < 4; ++tt)
                    acc[mt][tt] = __builtin_amdgcn_mfma_f32_16x16x32_bf16(
                        a[mt], b[tt], acc[mt][tt], 0, 0, 0);
        }
        #pragma unroll
        for (int mt = 0; mt < 2; ++mt)
            #pragma unroll
            for (int r = 0; r < 4; ++r) {
                int row = row0 + mt * 16 + quad * 4 + r;
                if (row < Nrows) {
                    if (c0w < 128) {            // waves 0,1 -> P0 (fp8)
                        #pragma unroll
                        for (int tt = 0; tt < 4; ++tt)
                            P0[(size_t)row * 128 + c0w + tt * 16 + l15] =
                                f2fp8(acc[mt][tt][r]);
                    } else {                    // waves 2,3 -> Q0 (bf16)
                        #pragma unroll
                        for (int tt = 0; tt < 4; ++tt)
                            Q0[(size_t)row * 128 + (c0w - 128) + tt * 16 + l15] =
                                f2bf(acc[mt][tt][r]);
                    }
                }
            }
        return;
    }
    // ---- bucket path ----
    __shared__ int hist[NBUCK];
    __shared__ int basel[NBUCK];
    int bid = blockIdx.x - gemmBlocks;
    for (int i = t; i < NBUCK; i += 256) hist[i] = 0;
    __syncthreads();
    int e0 = bid * EPB + t * 32;
    int d[32];
    if (e0 + 32 <= E) {
        #pragma unroll
        for (int q = 0; q < 8; ++q) {
            int4 v = *(const int4*)(dst + e0 + q * 4);
            d[q * 4 + 0] = v.x; d[q * 4 + 1] = v.y;
            d[q * 4 + 2] = v.z; d[q * 4 + 3] = v.w;
        }
    } else {
        #pragma unroll
        for (int j = 0; j < 32; ++j) d[j] = (e0 + j < E) ? dst[e0 + j] : -1;
    }
    #pragma unroll
    for (int j = 0; j < 32; ++j)
        if (d[j] >= 0) atomicAdd(&hist[d[j] >> 7], 1);
    __syncthreads();
    for (int i = t; i < NBUCK; i += 256) {
        int c = hist[i];
        basel[i] = (c > 0) ? atomicAdd(&cursor[i], c) : 0;
    }
    __syncthreads();
    for (int i = t; i < NBUCK; i += 256) hist[i] = 0;
    __syncthreads();
    int s[32];
    if (e0 + 32 <= E) {
        #pragma unroll
        for (int q = 0; q < 8; ++q) {
            int4 v = *(const int4*)(src + e0 + q * 4);
            s[q * 4 + 0] = v.x; s[q * 4 + 1] = v.y;
            s[q * 4 + 2] = v.z; s[q * 4 + 3] = v.w;
        }
    } else {
        #pragma unroll
        for (int j = 0; j < 32; ++j) s[j] = (e0 + j < E) ? src[e0 + j] : 0;
    }
    #pragma unroll
    for (int j = 0; j < 32; ++j) {
        if (d[j] < 0) continue;
        int b = d[j] >> 7;
        int r = atomicAdd(&hist[b], 1);
        bregion[(size_t)b * BCAP + basel[b] + r] = s[j] | ((d[j] & 127) << 20);
    }
}

// ---------------- finalize: block per bucket -> rowptr + csr ----------------
// Each block computes its own prefix over the 782 bucket counts (L2-hot).
__global__ __launch_bounds__(256) void k_csr(const int* __restrict__ cursor,
                                             const int* __restrict__ bregion,
                                             int* __restrict__ rowptr,
                                             int* __restrict__ csr, int Nn) {
    __shared__ int words[BCAP];
    __shared__ int hist[128], sc[128], rank[128];
    __shared__ int red[256];
    int b = blockIdx.x, t = threadIdx.x;
    int part = 0;
    for (int i = t; i < b; i += 256) part += cursor[i];
    red[t] = part;
    if (t < 128) { hist[t] = 0; rank[t] = 0; }
    __syncthreads();
    #pragma unroll
    for (int off = 128; off > 0; off >>= 1) {
        if (t < off) red[t] += red[t + off];
        __syncthreads();
    }
    int gbase = red[0];
    int cnt = cursor[b];
    for (int i = t; i < cnt; i += 256) {
        int w = bregion[(size_t)b * BCAP + i];
        words[i] = w;
        atomicAdd(&hist[w >> 20], 1);
    }
    __syncthreads();
    if (t < 128) sc[t] = hist[t];
    __syncthreads();
    #pragma unroll
    for (int off = 1; off < 128; off <<= 1) {
        int x = 0;
        if (t < 128 && t >= off) x = sc[t - off];
        __syncthreads();
        if (t < 128) sc[t] += x;
        __syncthreads();
    }
    if (t < 128) sc[t] -= hist[t];   // exclusive
    __syncthreads();
    if (t < 128) {
        int node = b * 128 + t;
        if (node <= Nn) rowptr[node] = gbase + sc[t];
    }
    for (int i = t; i < cnt; i += 256) {
        int w = words[i];
        int d7 = w >> 20;
        int r = atomicAdd(&rank[d7], 1);
        csr[gbase + sc[d7] + r] = w & 0xFFFFF;
    }
}

// ---------------- GEMM1: [P1 fp8 | Q1 bf16] = h_bf16[N x 128] @ W ----------------
__global__ __launch_bounds__(256) void k_gemm1(const unsigned short* __restrict__ Xv,
                                               const unsigned short* __restrict__ Wp,
                                               unsigned char* __restrict__ P1,
                                               unsigned short* __restrict__ Q1,
                                               int Nrows) {
    const int t = threadIdx.x;
    const int wave = t >> 6, lane = t & 63;
    const int quad = lane >> 4, l15 = lane & 15;
    const int row0 = blockIdx.x * 32;
    const int c0w = wave * 32;
    f32x4 acc[2][2];
    #pragma unroll
    for (int mt = 0; mt < 2; ++mt)
        #pragma unroll
        for (int tt = 0; tt < 2; ++tt) acc[mt][tt] = (f32x4){0.f, 0.f, 0.f, 0.f};
    #pragma unroll
    for (int kk = 0; kk < 4; ++kk) {
        const int k0 = kk * 32 + quad * 8;
        short8 a[2];
        #pragma unroll
        for (int mt = 0; mt < 2; ++mt) {
            int row = row0 + mt * 16 + l15;
            if (row > Nrows - 1) row = Nrows - 1;
            a[mt] = *(const short8*)(Xv + (size_t)row * 128 + k0);
        }
        short8 b[2];
        #pragma unroll
        for (int tt = 0; tt < 2; ++tt) {
            int tg = (c0w >> 4) + tt;
            b[tt] = *(const short8*)(Wp + ((size_t)(tg * 4 + kk) * 64 + lane) * 8);
        }
        #pragma unroll
        for (int mt = 0; mt < 2; ++mt)
            #pragma unroll
            for (int tt = 0; tt < 2; ++tt)
                acc[mt][tt] = __builtin_amdgcn_mfma_f32_16x16x32_bf16(
                    a[mt], b[tt], acc[mt][tt], 0, 0, 0);
    }
    #pragma unroll
    for (int mt = 0; mt < 2; ++mt)
        #pragma unroll
        for (int r = 0; r < 4; ++r) {
            int row = row0 + mt * 16 + quad * 4 + r;
            if (row < Nrows) {
                if (c0w < 64) {                 // waves 0,1 -> P1 (fp8)
                    #pragma unroll
                    for (int tt = 0; tt < 2; ++tt)
                        P1[(size_t)row * 64 + c0w + tt * 16 + l15] =
                            f2fp8(acc[mt][tt][r]);
                } else {                        // waves 2,3 -> Q1 (bf16)
                    #pragma unroll
                    for (int tt = 0; tt < 2; ++tt)
                        Q1[(size_t)row * 64 + (c0w - 64) + tt * 16 + l15] =
                            f2bf(acc[mt][tt][r]);
                }
            }
        }
}

// ---------------- aggregation ----------------
// agg0: wave/node, 8 nbrs per pass (8 lanes x 16B fp8 = 128B row), 2x unroll.
__global__ __launch_bounds__(256) void k_agg0(const unsigned char* __restrict__ P0,
                                              const unsigned short* __restrict__ Q0,
                                              const int* __restrict__ rowptr,
                                              const int* __restrict__ csr,
                                              const float* __restrict__ bl0,
                                              unsigned short* __restrict__ h, int Nn) {
    int wave = threadIdx.x >> 6, lane = threadIdx.x & 63;
    int n = blockIdx.x * 4 + wave;
    if (n >= Nn) return;
    int g = lane >> 3, l7 = lane & 7;
    int st = rowptr[n], dg = rowptr[n + 1] - st;
    float acc[16] = {};
    int e = 0;
    for (; e + 16 <= dg; e += 16) {
        int s0 = csr[st + e + g];
        int s1 = csr[st + e + 8 + g];
        uint4 w0 = *(const uint4*)(P0 + (size_t)s0 * 128 + l7 * 16);
        uint4 w1 = *(const uint4*)(P0 + (size_t)s1 * 128 + l7 * 16);
        acc_fp8x4(w0.x, acc + 0);  acc_fp8x4(w0.y, acc + 4);
        acc_fp8x4(w0.z, acc + 8);  acc_fp8x4(w0.w, acc + 12);
        acc_fp8x4(w1.x, acc + 0);  acc_fp8x4(w1.y, acc + 4);
        acc_fp8x4(w1.z, acc + 8);  acc_fp8x4(w1.w, acc + 12);
    }
    for (; e + 8 <= dg; e += 8) {
        int s0 = csr[st + e + g];
        uint4 w0 = *(const uint4*)(P0 + (size_t)s0 * 128 + l7 * 16);
        acc_fp8x4(w0.x, acc + 0);  acc_fp8x4(w0.y, acc + 4);
        acc_fp8x4(w0.z, acc + 8);  acc_fp8x4(w0.w, acc + 12);
    }
    if (e + g < dg) {
        int s0 = csr[st + e + g];
        uint4 w0 = *(const uint4*)(P0 + (size_t)s0 * 128 + l7 * 16);
        acc_fp8x4(w0.x, acc + 0);  acc_fp8x4(w0.y, acc + 4);
        acc_fp8x4(w0.z, acc + 8);  acc_fp8x4(w0.w, acc + 12);
    }
    #pragma unroll
    for (int j = 0; j < 16; ++j) {
        acc[j] += __shfl_xor(acc[j], 8);
        acc[j] += __shfl_xor(acc[j], 16);
        acc[j] += __shfl_xor(acc[j], 32);
    }
    if (lane < 8) {                 // lane l7 owns cols [l7*16, l7*16+16)
        float inv = 1.f / fmaxf((float)dg, 1.f);
        short8 q0 = *(const short8*)(Q0 + (size_t)n * 128 + l7 * 16);
        short8 q1 = *(const short8*)(Q0 + (size_t)n * 128 + l7 * 16 + 8);
        float bb[16];
        *(float4*)(bb + 0)  = *(const float4*)(bl0 + l7 * 16);
        *(float4*)(bb + 4)  = *(const float4*)(bl0 + l7 * 16 + 4);
        *(float4*)(bb + 8)  = *(const float4*)(bl0 + l7 * 16 + 8);
        *(float4*)(bb + 12) = *(const float4*)(bl0 + l7 * 16 + 12);
        short8 o0, o1;
        #pragma unroll
        for (int j = 0; j < 8; ++j) {
            float v = fmaxf(acc[j] * inv + bb[j] + bf2f_s(q0[j]), 0.f);
            o0[j] = (short)f2bf(v);
        }
        #pragma unroll
        for (int j = 0; j < 8; ++j) {
            float v = fmaxf(acc[8 + j] * inv + bb[8 + j] + bf2f_s(q1[j]), 0.f);
            o1[j] = (short)f2bf(v);
        }
        *(short8*)(h + (size_t)n * 128 + l7 * 16) = o0;
        *(short8*)(h + (size_t)n * 128 + l7 * 16 + 8) = o1;
    }
}

// agg1: wave/node, 16 nbrs per pass (4 lanes x 16B fp8 = 64B row).
__global__ __launch_bounds__(256) void k_agg1(const unsigned char* __restrict__ P1,
                                              const unsigned short* __restrict__ Q1,
                                              const int* __restrict__ rowptr,
                                              const int* __restrict__ csr,
                                              const float* __restrict__ bl1,
                                              float* __restrict__ out, int Nn) {
    int wave = threadIdx.x >> 6, lane = threadIdx.x & 63;
    int n = blockIdx.x * 4 + wave;
    if (n >= Nn) return;
    int g = lane >> 2, l3 = lane & 3;
    int st = rowptr[n], dg = rowptr[n + 1] - st;
    float acc[16] = {};
    int e = 0;
    for (; e + 16 <= dg; e += 16) {
        int s0 = csr[st + e + g];
        uint4 w0 = *(const uint4*)(P1 + (size_t)s0 * 64 + l3 * 16);
        acc_fp8x4(w0.x, acc + 0);  acc_fp8x4(w0.y, acc + 4);
        acc_fp8x4(w0.z, acc + 8);  acc_fp8x4(w0.w, acc + 12);
    }
    if (e + g < dg) {
        int s0 = csr[st + e + g];
        uint4 w0 = *(const uint4*)(P1 + (size_t)s0 * 64 + l3 * 16);
        acc_fp8x4(w0.x, acc + 0);  acc_fp8x4(w0.y, acc + 4);
        acc_fp8x4(w0.z, acc + 8);  acc_fp8x4(w0.w, acc + 12);
    }
    #pragma unroll
    for (int j = 0; j < 16; ++j) {
        acc[j] += __shfl_xor(acc[j], 4);
        acc[j] += __shfl_xor(acc[j], 8);
        acc[j] += __shfl_xor(acc[j], 16);
        acc[j] += __shfl_xor(acc[j], 32);
    }
    if (lane < 4) {                 // lane l3 owns cols [l3*16, l3*16+16)
        float inv = 1.f / fmaxf((float)dg, 1.f);
        short8 q0 = *(const short8*)(Q1 + (size_t)n * 64 + l3 * 16);
        short8 q1 = *(const short8*)(Q1 + (size_t)n * 64 + l3 * 16 + 8);
        float bb[16];
        *(float4*)(bb + 0)  = *(const float4*)(bl1 + l3 * 16);
        *(float4*)(bb + 4)  = *(const float4*)(bl1 + l3 * 16 + 4);
        *(float4*)(bb + 8)  = *(const float4*)(bl1 + l3 * 16 + 8);
        *(float4*)(bb + 12) = *(const float4*)(bl1 + l3 * 16 + 12);
        float4 o[4];
        #pragma unroll
        for (int j = 0; j < 8; ++j)
            ((float*)o)[j] = acc[j] * inv + bb[j] + bf2f_s(q0[j]);
        #pragma unroll
        for (int j = 0; j < 8; ++j)
            ((float*)o)[8 + j] = acc[8 + j] * inv + bb[8 + j] + bf2f_s(q1[j]);
        #pragma unroll
        for (int q = 0; q < 4; ++q)
            *(float4*)(out + (size_t)n * 64 + l3 * 16 + q * 4) = o[q];
    }
}

extern "C" void kernel_launch(void* const* d_in, const int* in_sizes, int n_in,
                              void* d_out, int out_size, void* d_ws, size_t ws_size,
                              hipStream_t stream) {
    const float* x   = (const float*)d_in[0];
    const int* eidx  = (const int*)d_in[1];
    const float* Wl0 = (const float*)d_in[2];
    const float* bl0 = (const float*)d_in[3];
    const float* Wr0 = (const float*)d_in[4];
    const float* Wl1 = (const float*)d_in[5];
    const float* bl1 = (const float*)d_in[6];
    const float* Wr1 = (const float*)d_in[7];
    float* out = (float*)d_out;

    const int N = in_sizes[0] / 128;   // 100000
    const int E = in_sizes[1] / 2;     // 1600000
    const int* src = eidx;
    const int* dst = eidx + E;

    // workspace layout (sections 16B aligned)
    int* rowptr  = (int*)d_ws;                          // N+4
    int* cursor  = rowptr + (N + 4);                    // 784
    int* bregion = cursor + 784;                        // NBUCK*BCAP
    int* csr     = bregion + (size_t)NBUCK * BCAP;      // E
    unsigned short* Wp0 = (unsigned short*)(csr + E);   // 32768
    unsigned short* Wp1 = Wp0 + 32768;                  // 16384
    unsigned char*  P0  = (unsigned char*)(Wp1 + 16384);      // N*128 fp8
    unsigned short* Q0  = (unsigned short*)(P0 + (size_t)N * 128);  // N*128 bf16
    unsigned short* h   = Q0 + (size_t)N * 128;               // N*128 bf16
    unsigned char*  P1  = (unsigned char*)(h + (size_t)N * 128);    // N*64 fp8
    unsigned short* Q1  = (unsigned short*)(P1 + (size_t)N * 64);   // N*64 bf16

    hipMemsetAsync(cursor, 0, NBUCK * sizeof(int), stream);

    k_pack<<<(256 * 16 + 255) / 256, 256, 0, stream>>>(Wl0, Wr0, 128, 256, Wp0);
    k_pack<<<(128 * 16 + 255) / 256, 256, 0, stream>>>(Wl1, Wr1, 64, 128, Wp1);

    int gemmBlocks = (N + 31) / 32;               // 3125
    int nbb = (E + EPB - 1) / EPB;                // 196
    k_gemm0_bucket<<<gemmBlocks + nbb, 256, 0, stream>>>(
        x, Wp0, P0, Q0, N, src, dst, cursor, bregion, E, gemmBlocks);
    k_csr<<<NBUCK, 256, 0, stream>>>(cursor, bregion, rowptr, csr, N);

    k_agg0<<<(N + 3) / 4, 256, 0, stream>>>(P0, Q0, rowptr, csr, bl0, h, N);
    k_gemm1<<<(N + 31) / 32, 256, 0, stream>>>(h, Wp1, P1, Q1, N);
    k_agg1<<<(N + 3) / 4, 256, 0, stream>>>(P1, Q1, rowptr, csr, bl1, out, N);
}

// Round 7
// 297.719 us; speedup vs baseline: 1.2488x; 1.1005x over previous
//
#include <hip/hip_runtime.h>

// GraphSAGE 2-layer, N=100000, IN=HID=128, OUT=64, E=1.6M, fp32 in/out.
//   agg @ Wl == segsum((h@Wl)[src])/cnt  -> GEMM first, then gather-mean.
// Round 7: aggregation restructured lane-group-per-node (no butterfly):
//   agg0: 8-lane group owns one 128B fp8 row; 8 nodes/wave; lane keeps its
//         16 cols in regs across all neighbors. agg1: 4-lane group, 16 nodes/wave.
//   Kills the 64x ds_swizzle reduction + 4/64-lane epilogue that made R6's
//   k_agg1 overhead-bound (75us at only 1.57TB/s).

typedef short short8 __attribute__((ext_vector_type(8)));
typedef float f32x4 __attribute__((ext_vector_type(4)));
typedef float f32x2 __attribute__((ext_vector_type(2)));

#define NBUCK 782      // ceil(100000 / 128)
#define BCAP  3072     // per-bucket region capacity (avg 2046, sigma 45)
#define EPB   8192     // edges per bucket-build block (256 thr x 32)

static __device__ __forceinline__ unsigned short f2bf(float f) {
    union { float f; unsigned u; } c; c.f = f;
    unsigned u = c.u + 0x7fffu + ((c.u >> 16) & 1u);   // RNE
    return (unsigned short)(u >> 16);
}
static __device__ __forceinline__ float bf2f(unsigned short b) {
    union { unsigned u; float f; } c; c.u = ((unsigned)b) << 16;
    return c.f;
}
static __device__ __forceinline__ float bf2f_s(short b) {
    return bf2f((unsigned short)b);
}

// fp8 e4m3fn (OCP) software encode, RNE, exact subnormals, clamp to 448.
static __device__ __forceinline__ unsigned char f2fp8(float x) {
    union { float f; unsigned u; } c; c.f = x;
    unsigned s = (c.u >> 24) & 0x80u;
    float a = __builtin_fabsf(x);
    if (a < 0.015625f) {                        // subnormal: m = RNE(a*512)
        int m = (int)rintf(a * 512.0f);         // 0..8 (8 carries to 2^-6)
        return (unsigned char)(s | (unsigned)m);
    }
    unsigned u = c.u + 0x7ffffu + ((c.u >> 20) & 1u);
    int e = (int)((u >> 23) & 0xff) - 120;      // e4m3 biased exponent
    unsigned m = (u >> 20) & 7u;
    if (e > 15) { e = 15; m = 6; }              // clamp to 448, never NaN
    return (unsigned char)(s | (unsigned)(e << 3) | m);
}

// decode 4 fp8 from one dword, accumulate into a[0..3]
static __device__ __forceinline__ void acc_fp8x4(unsigned w, float* a) {
#if __has_builtin(__builtin_amdgcn_cvt_pk_f32_fp8)
    f32x2 lo = __builtin_amdgcn_cvt_pk_f32_fp8((int)w, false);
    f32x2 hi = __builtin_amdgcn_cvt_pk_f32_fp8((int)w, true);
    a[0] += lo[0]; a[1] += lo[1]; a[2] += hi[0]; a[3] += hi[1];
#else
    #pragma unroll
    for (int j = 0; j < 4; ++j) {
        unsigned b = (w >> (8 * j)) & 0xffu;
        union { unsigned u; float f; } c;
        c.u = ((b & 0x80u) << 24) | ((b & 0x7fu) << 20);
        a[j] += c.f * 0x1p120f;                 // exact for all e4m3fn values
    }
#endif
}
static __device__ __forceinline__ void acc_row16(uint4 w, float* a) {
    acc_fp8x4(w.x, a + 0);  acc_fp8x4(w.y, a + 4);
    acc_fp8x4(w.z, a + 8);  acc_fp8x4(w.w, a + 12);
}

// ---------------- weight pack into MFMA B-fragment order ----------------
__global__ __launch_bounds__(256) void k_pack(const float* __restrict__ WA,
                                              const float* __restrict__ WB,
                                              int CA, int NC,
                                              unsigned short* __restrict__ Wp) {
    int tid = blockIdx.x * 256 + threadIdx.x;
    if (tid >= NC * 16) return;
    int lane = tid & 63, kk = (tid >> 6) & 3, tg = tid >> 8;
    int l15 = lane & 15, quad = lane >> 4;
    int c = tg * 16 + l15;
    const float* W = (c < CA) ? WA : WB;
    int cc = (c < CA) ? c : c - CA;
    short8 v;
    #pragma unroll
    for (int j = 0; j < 8; ++j) {
        int k = kk * 32 + quad * 8 + j;
        v[j] = (short)f2bf(W[(size_t)k * CA + cc]);
    }
    *(short8*)(Wp + (size_t)tid * 8) = v;
}

// ---------------- fused: GEMM0 (blocks < gemmBlocks) | bucket scatter ----------------
__global__ __launch_bounds__(256) void k_gemm0_bucket(
        const float* __restrict__ X, const unsigned short* __restrict__ Wp,
        unsigned char* __restrict__ P0, unsigned short* __restrict__ Q0, int Nrows,
        const int* __restrict__ src, const int* __restrict__ dst,
        int* __restrict__ cursor, int* __restrict__ bregion,
        int E, int gemmBlocks) {
    const int t = threadIdx.x;
    if ((int)blockIdx.x < gemmBlocks) {
        const int wave = t >> 6, lane = t & 63;
        const int quad = lane >> 4, l15 = lane & 15;
        const int row0 = blockIdx.x * 32;
        const int c0w = wave * 64;
        f32x4 acc[2][4];
        #pragma unroll
        for (int mt = 0; mt < 2; ++mt)
            #pragma unroll
            for (int tt = 0; tt < 4; ++tt) acc[mt][tt] = (f32x4){0.f, 0.f, 0.f, 0.f};
        #pragma unroll
        for (int kk = 0; kk < 4; ++kk) {
            const int k0 = kk * 32 + quad * 8;
            short8 a[2];
            #pragma unroll
            for (int mt = 0; mt < 2; ++mt) {
                int row = row0 + mt * 16 + l15;
                if (row > Nrows - 1) row = Nrows - 1;
                const float* xp = X + (size_t)row * 128 + k0;
                float4 f0 = *(const float4*)xp;
                float4 f1 = *(const float4*)(xp + 4);
                short8 v;
                v[0] = (short)f2bf(f0.x); v[1] = (short)f2bf(f0.y);
                v[2] = (short)f2bf(f0.z); v[3] = (short)f2bf(f0.w);
                v[4] = (short)f2bf(f1.x); v[5] = (short)f2bf(f1.y);
                v[6] = (short)f2bf(f1.z); v[7] = (short)f2bf(f1.w);
                a[mt] = v;
            }
            short8 b[4];
            #pragma unroll
            for (int tt = 0; tt < 4; ++tt) {
                int tg = (c0w >> 4) + tt;
                b[tt] = *(const short8*)(Wp + ((size_t)(tg * 4 + kk) * 64 + lane) * 8);
            }
            #pragma unroll
            for (int mt = 0; mt < 2; ++mt)
                #pragma unroll
                for (int tt = 0; tt < 4; ++tt)
                    acc[mt][tt] = __builtin_amdgcn_mfma_f32_16x16x32_bf16(
                        a[mt], b[tt], acc[mt][tt], 0, 0, 0);
        }
        #pragma unroll
        for (int mt = 0; mt < 2; ++mt)
            #pragma unroll
            for (int r = 0; r < 4; ++r) {
                int row = row0 + mt * 16 + quad * 4 + r;
                if (row < Nrows) {
                    if (c0w < 128) {            // waves 0,1 -> P0 (fp8)
                        #pragma unroll
                        for (int tt = 0; tt < 4; ++tt)
                            P0[(size_t)row * 128 + c0w + tt * 16 + l15] =
                                f2fp8(acc[mt][tt][r]);
                    } else {                    // waves 2,3 -> Q0 (bf16)
                        #pragma unroll
                        for (int tt = 0; tt < 4; ++tt)
                            Q0[(size_t)row * 128 + (c0w - 128) + tt * 16 + l15] =
                                f2bf(acc[mt][tt][r]);
                    }
                }
            }
        return;
    }
    // ---- bucket path ----
    __shared__ int hist[NBUCK];
    __shared__ int basel[NBUCK];
    int bid = blockIdx.x - gemmBlocks;
    for (int i = t; i < NBUCK; i += 256) hist[i] = 0;
    __syncthreads();
    int e0 = bid * EPB + t * 32;
    int d[32];
    if (e0 + 32 <= E) {
        #pragma unroll
        for (int q = 0; q < 8; ++q) {
            int4 v = *(const int4*)(dst + e0 + q * 4);
            d[q * 4 + 0] = v.x; d[q * 4 + 1] = v.y;
            d[q * 4 + 2] = v.z; d[q * 4 + 3] = v.w;
        }
    } else {
        #pragma unroll
        for (int j = 0; j < 32; ++j) d[j] = (e0 + j < E) ? dst[e0 + j] : -1;
    }
    #pragma unroll
    for (int j = 0; j < 32; ++j)
        if (d[j] >= 0) atomicAdd(&hist[d[j] >> 7], 1);
    __syncthreads();
    for (int i = t; i < NBUCK; i += 256) {
        int c = hist[i];
        basel[i] = (c > 0) ? atomicAdd(&cursor[i], c) : 0;
    }
    __syncthreads();
    for (int i = t; i < NBUCK; i += 256) hist[i] = 0;
    __syncthreads();
    int s[32];
    if (e0 + 32 <= E) {
        #pragma unroll
        for (int q = 0; q < 8; ++q) {
            int4 v = *(const int4*)(src + e0 + q * 4);
            s[q * 4 + 0] = v.x; s[q * 4 + 1] = v.y;
            s[q * 4 + 2] = v.z; s[q * 4 + 3] = v.w;
        }
    } else {
        #pragma unroll
        for (int j = 0; j < 32; ++j) s[j] = (e0 + j < E) ? src[e0 + j] : 0;
    }
    #pragma unroll
    for (int j = 0; j < 32; ++j) {
        if (d[j] < 0) continue;
        int b = d[j] >> 7;
        int r = atomicAdd(&hist[b], 1);
        bregion[(size_t)b * BCAP + basel[b] + r] = s[j] | ((d[j] & 127) << 20);
    }
}

// ---------------- finalize: block per bucket -> rowptr + csr ----------------
__global__ __launch_bounds__(256) void k_csr(const int* __restrict__ cursor,
                                             const int* __restrict__ bregion,
                                             int* __restrict__ rowptr,
                                             int* __restrict__ csr, int Nn) {
    __shared__ int words[BCAP];
    __shared__ int hist[128], sc[128], rank[128];
    __shared__ int red[256];
    int b = blockIdx.x, t = threadIdx.x;
    int part = 0;
    for (int i = t; i < b; i += 256) part += cursor[i];
    red[t] = part;
    if (t < 128) { hist[t] = 0; rank[t] = 0; }
    __syncthreads();
    #pragma unroll
    for (int off = 128; off > 0; off >>= 1) {
        if (t < off) red[t] += red[t + off];
        __syncthreads();
    }
    int gbase = red[0];
    int cnt = cursor[b];
    for (int i = t; i < cnt; i += 256) {
        int w = bregion[(size_t)b * BCAP + i];
        words[i] = w;
        atomicAdd(&hist[w >> 20], 1);
    }
    __syncthreads();
    if (t < 128) sc[t] = hist[t];
    __syncthreads();
    #pragma unroll
    for (int off = 1; off < 128; off <<= 1) {
        int x = 0;
        if (t < 128 && t >= off) x = sc[t - off];
        __syncthreads();
        if (t < 128) sc[t] += x;
        __syncthreads();
    }
    if (t < 128) sc[t] -= hist[t];   // exclusive
    __syncthreads();
    if (t < 128) {
        int node = b * 128 + t;
        if (node <= Nn) rowptr[node] = gbase + sc[t];
    }
    for (int i = t; i < cnt; i += 256) {
        int w = words[i];
        int d7 = w >> 20;
        int r = atomicAdd(&rank[d7], 1);
        csr[gbase + sc[d7] + r] = w & 0xFFFFF;
    }
}

// ---------------- GEMM1: [P1 fp8 | Q1 bf16] = h_bf16[N x 128] @ W ----------------
__global__ __launch_bounds__(256) void k_gemm1(const unsigned short* __restrict__ Xv,
                                               const unsigned short* __restrict__ Wp,
                                               unsigned char* __restrict__ P1,
                                               unsigned short* __restrict__ Q1,
                                               int Nrows) {
    const int t = threadIdx.x;
    const int wave = t >> 6, lane = t & 63;
    const int quad = lane >> 4, l15 = lane & 15;
    const int row0 = blockIdx.x * 32;
    const int c0w = wave * 32;
    f32x4 acc[2][2];
    #pragma unroll
    for (int mt = 0; mt < 2; ++mt)
        #pragma unroll
        for (int tt = 0; tt < 2; ++tt) acc[mt][tt] = (f32x4){0.f, 0.f, 0.f, 0.f};
    #pragma unroll
    for (int kk = 0; kk < 4; ++kk) {
        const int k0 = kk * 32 + quad * 8;
        short8 a[2];
        #pragma unroll
        for (int mt = 0; mt < 2; ++mt) {
            int row = row0 + mt * 16 + l15;
            if (row > Nrows - 1) row = Nrows - 1;
            a[mt] = *(const short8*)(Xv + (size_t)row * 128 + k0);
        }
        short8 b[2];
        #pragma unroll
        for (int tt = 0; tt < 2; ++tt) {
            int tg = (c0w >> 4) + tt;
            b[tt] = *(const short8*)(Wp + ((size_t)(tg * 4 + kk) * 64 + lane) * 8);
        }
        #pragma unroll
        for (int mt = 0; mt < 2; ++mt)
            #pragma unroll
            for (int tt = 0; tt < 2; ++tt)
                acc[mt][tt] = __builtin_amdgcn_mfma_f32_16x16x32_bf16(
                    a[mt], b[tt], acc[mt][tt], 0, 0, 0);
    }
    #pragma unroll
    for (int mt = 0; mt < 2; ++mt)
        #pragma unroll
        for (int r = 0; r < 4; ++r) {
            int row = row0 + mt * 16 + quad * 4 + r;
            if (row < Nrows) {
                if (c0w < 64) {                 // waves 0,1 -> P1 (fp8)
                    #pragma unroll
                    for (int tt = 0; tt < 2; ++tt)
                        P1[(size_t)row * 64 + c0w + tt * 16 + l15] =
                            f2fp8(acc[mt][tt][r]);
                } else {                        // waves 2,3 -> Q1 (bf16)
                    #pragma unroll
                    for (int tt = 0; tt < 2; ++tt)
                        Q1[(size_t)row * 64 + (c0w - 64) + tt * 16 + l15] =
                            f2bf(acc[mt][tt][r]);
                }
            }
        }
}

// ---------------- aggregation: lane-group per node, no cross-lane reduce ----
// agg0: 8-lane group owns the 128B fp8 row; 8 nodes/wave; lane keeps 16 cols.
__global__ __launch_bounds__(256) void k_agg0(const unsigned char* __restrict__ P0,
                                              const unsigned short* __restrict__ Q0,
                                              const int* __restrict__ rowptr,
                                              const int* __restrict__ csr,
                                              const float* __restrict__ bl0,
                                              unsigned short* __restrict__ h, int Nn) {
    int wave = threadIdx.x >> 6, lane = threadIdx.x & 63;
    int g = lane >> 3, l7 = lane & 7;
    int n = (blockIdx.x * 4 + wave) * 8 + g;
    bool live = (n < Nn);
    int st = 0, dg = 0;
    if (live) { st = rowptr[n]; dg = rowptr[n + 1] - st; }
    float acc[16] = {};
    int e = 0;
    for (; e + 2 <= dg; e += 2) {
        int s0 = csr[st + e];
        int s1 = csr[st + e + 1];
        uint4 w0 = *(const uint4*)(P0 + (size_t)s0 * 128 + l7 * 16);
        uint4 w1 = *(const uint4*)(P0 + (size_t)s1 * 128 + l7 * 16);
        acc_row16(w0, acc);
        acc_row16(w1, acc);
    }
    if (e < dg) {
        int s0 = csr[st + e];
        uint4 w0 = *(const uint4*)(P0 + (size_t)s0 * 128 + l7 * 16);
        acc_row16(w0, acc);
    }
    if (live) {
        float inv = 1.f / fmaxf((float)dg, 1.f);
        short8 q0 = *(const short8*)(Q0 + (size_t)n * 128 + l7 * 16);
        short8 q1 = *(const short8*)(Q0 + (size_t)n * 128 + l7 * 16 + 8);
        float bb[16];
        *(float4*)(bb + 0)  = *(const float4*)(bl0 + l7 * 16);
        *(float4*)(bb + 4)  = *(const float4*)(bl0 + l7 * 16 + 4);
        *(float4*)(bb + 8)  = *(const float4*)(bl0 + l7 * 16 + 8);
        *(float4*)(bb + 12) = *(const float4*)(bl0 + l7 * 16 + 12);
        short8 o0, o1;
        #pragma unroll
        for (int j = 0; j < 8; ++j)
            o0[j] = (short)f2bf(fmaxf(acc[j] * inv + bb[j] + bf2f_s(q0[j]), 0.f));
        #pragma unroll
        for (int j = 0; j < 8; ++j)
            o1[j] = (short)f2bf(fmaxf(acc[8 + j] * inv + bb[8 + j] + bf2f_s(q1[j]), 0.f));
        *(short8*)(h + (size_t)n * 128 + l7 * 16) = o0;
        *(short8*)(h + (size_t)n * 128 + l7 * 16 + 8) = o1;
    }
}

// agg1: 4-lane group owns the 64B fp8 row; 16 nodes/wave; lane keeps 16 cols.
__global__ __launch_bounds__(256) void k_agg1(const unsigned char* __restrict__ P1,
                                              const unsigned short* __restrict__ Q1,
                                              const int* __restrict__ rowptr,
                                              const int* __restrict__ csr,
                                              const float* __restrict__ bl1,
                                              float* __restrict__ out, int Nn) {
    int wave = threadIdx.x >> 6, lane = threadIdx.x & 63;
    int g = lane >> 2, l3 = lane & 3;
    int n = (blockIdx.x * 4 + wave) * 16 + g;
    bool live = (n < Nn);
    int st = 0, dg = 0;
    if (live) { st = rowptr[n]; dg = rowptr[n + 1] - st; }
    float acc[16] = {};
    int e = 0;
    for (; e + 2 <= dg; e += 2) {
        int s0 = csr[st + e];
        int s1 = csr[st + e + 1];
        uint4 w0 = *(const uint4*)(P1 + (size_t)s0 * 64 + l3 * 16);
        uint4 w1 = *(const uint4*)(P1 + (size_t)s1 * 64 + l3 * 16);
        acc_row16(w0, acc);
        acc_row16(w1, acc);
    }
    if (e < dg) {
        int s0 = csr[st + e];
        uint4 w0 = *(const uint4*)(P1 + (size_t)s0 * 64 + l3 * 16);
        acc_row16(w0, acc);
    }
    if (live) {
        float inv = 1.f / fmaxf((float)dg, 1.f);
        short8 q0 = *(const short8*)(Q1 + (size_t)n * 64 + l3 * 16);
        short8 q1 = *(const short8*)(Q1 + (size_t)n * 64 + l3 * 16 + 8);
        float bb[16];
        *(float4*)(bb + 0)  = *(const float4*)(bl1 + l3 * 16);
        *(float4*)(bb + 4)  = *(const float4*)(bl1 + l3 * 16 + 4);
        *(float4*)(bb + 8)  = *(const float4*)(bl1 + l3 * 16 + 8);
        *(float4*)(bb + 12) = *(const float4*)(bl1 + l3 * 16 + 12);
        float4 o[4];
        #pragma unroll
        for (int j = 0; j < 8; ++j)
            ((float*)o)[j] = acc[j] * inv + bb[j] + bf2f_s(q0[j]);
        #pragma unroll
        for (int j = 0; j < 8; ++j)
            ((float*)o)[8 + j] = acc[8 + j] * inv + bb[8 + j] + bf2f_s(q1[j]);
        #pragma unroll
        for (int q = 0; q < 4; ++q)
            *(float4*)(out + (size_t)n * 64 + l3 * 16 + q * 4) = o[q];
    }
}

extern "C" void kernel_launch(void* const* d_in, const int* in_sizes, int n_in,
                              void* d_out, int out_size, void* d_ws, size_t ws_size,
                              hipStream_t stream) {
    const float* x   = (const float*)d_in[0];
    const int* eidx  = (const int*)d_in[1];
    const float* Wl0 = (const float*)d_in[2];
    const float* bl0 = (const float*)d_in[3];
    const float* Wr0 = (const float*)d_in[4];
    const float* Wl1 = (const float*)d_in[5];
    const float* bl1 = (const float*)d_in[6];
    const float* Wr1 = (const float*)d_in[7];
    float* out = (float*)d_out;

    const int N = in_sizes[0] / 128;   // 100000
    const int E = in_sizes[1] / 2;     // 1600000
    const int* src = eidx;
    const int* dst = eidx + E;

    // workspace layout (sections 16B aligned)
    int* rowptr  = (int*)d_ws;                          // N+4
    int* cursor  = rowptr + (N + 4);                    // 784
    int* bregion = cursor + 784;                        // NBUCK*BCAP
    int* csr     = bregion + (size_t)NBUCK * BCAP;      // E
    unsigned short* Wp0 = (unsigned short*)(csr + E);   // 32768
    unsigned short* Wp1 = Wp0 + 32768;                  // 16384
    unsigned char*  P0  = (unsigned char*)(Wp1 + 16384);      // N*128 fp8
    unsigned short* Q0  = (unsigned short*)(P0 + (size_t)N * 128);  // N*128 bf16
    unsigned short* h   = Q0 + (size_t)N * 128;               // N*128 bf16
    unsigned char*  P1  = (unsigned char*)(h + (size_t)N * 128);    // N*64 fp8
    unsigned short* Q1  = (unsigned short*)(P1 + (size_t)N * 64);   // N*64 bf16

    hipMemsetAsync(cursor, 0, NBUCK * sizeof(int), stream);

    k_pack<<<(256 * 16 + 255) / 256, 256, 0, stream>>>(Wl0, Wr0, 128, 256, Wp0);
    k_pack<<<(128 * 16 + 255) / 256, 256, 0, stream>>>(Wl1, Wr1, 64, 128, Wp1);

    int gemmBlocks = (N + 31) / 32;               // 3125
    int nbb = (E + EPB - 1) / EPB;                // 196
    k_gemm0_bucket<<<gemmBlocks + nbb, 256, 0, stream>>>(
        x, Wp0, P0, Q0, N, src, dst, cursor, bregion, E, gemmBlocks);
    k_csr<<<NBUCK, 256, 0, stream>>>(cursor, bregion, rowptr, csr, N);

    k_agg0<<<(N + 31) / 32, 256, 0, stream>>>(P0, Q0, rowptr, csr, bl0, h, N);
    k_gemm1<<<(N + 31) / 32, 256, 0, stream>>>(h, Wp1, P1, Q1, N);
    k_agg1<<<(N + 63) / 64, 256, 0, stream>>>(P1, Q1, rowptr, csr, bl1, out, N);
}